// Round 18
// baseline (275.216 us; speedup 1.0000x reference)
//
#include <hip/hip_runtime.h>
#include <hip/hip_bf16.h>

typedef unsigned short u16;
typedef unsigned int   u32;

static constexpr int Bc = 8, Ac = 64, Tc = 128, Cc = 256, Hc = 8;
static constexpr int NROW = Bc * Ac * Tc;   // 65536 tokens
static constexpr int DH = Cc / Hc;          // 32

__device__ __forceinline__ float bf2f(u16 h) {
    u32 u = ((u32)h) << 16; float f; __builtin_memcpy(&f, &u, 4); return f;
}
// fast f32->bf16: round-half-away (2 ops vs 5 for full RNE; differs from RNE
// only on exact ties, measure-zero for real data)
__device__ __forceinline__ u16 f2bf(float f) {
    u32 u; __builtin_memcpy(&u, &f, 4);
    return (u16)((u + 0x8000u) >> 16);
}

// sigmoid-GELU: x*sigmoid(1.702x); error budget verified r15-r17 (absmax 0.052)
__device__ __forceinline__ float gelu_f(float x) {
    return x / (1.0f + __expf(-1.702f * x));
}

typedef __attribute__((ext_vector_type(8))) short  short8v;
typedef __attribute__((ext_vector_type(4))) float  float4v;

__device__ __forceinline__ void gload16(const void* g, const void* lds) {
    __builtin_amdgcn_global_load_lds(
        (const __attribute__((address_space(1))) void*)g,
        (__attribute__((address_space(3))) void*)lds, 16, 0, 0);
}

#define MFMA16(a, b, c) __builtin_amdgcn_mfma_f32_16x16x32_bf16((a), (b), (c), 0, 0, 0)

// ---- prep: LN1 (blocks 0..16383) + weight casts (blocks 16384..) in ONE launch ----
__global__ __launch_bounds__(256) void prep_kernel(
        const float* __restrict__ x, const float* __restrict__ ln1w,
        const float* __restrict__ ln1b, u16* __restrict__ x1,
        const float* __restrict__ a, int na, const float* __restrict__ b, int nb,
        const float* __restrict__ c, int nc, const float* __restrict__ d, int nd,
        u16* oa, u16* ob, u16* oc, u16* od) {
    const int blk = blockIdx.x;
    if (blk < NROW / 4) {
        int row  = blk * 4 + (threadIdx.x >> 6);
        int lane = threadIdx.x & 63;
        const float* rp = x + (size_t)row * Cc + lane * 4;
        float4 v = *(const float4*)rp;
        float s  = v.x + v.y + v.z + v.w;
        float sq = v.x * v.x + v.y * v.y + v.z * v.z + v.w * v.w;
        for (int off = 32; off; off >>= 1) { s += __shfl_xor(s, off); sq += __shfl_xor(sq, off); }
        float mean = s * (1.f / Cc);
        float rs = rsqrtf(sq * (1.f / Cc) - mean * mean + 1e-5f);
        int c0 = lane * 4;
        ushort4 ov;
        ov.x = f2bf((v.x - mean) * rs * ln1w[c0 + 0] + ln1b[c0 + 0]);
        ov.y = f2bf((v.y - mean) * rs * ln1w[c0 + 1] + ln1b[c0 + 1]);
        ov.z = f2bf((v.z - mean) * rs * ln1w[c0 + 2] + ln1b[c0 + 2]);
        ov.w = f2bf((v.w - mean) * rs * ln1w[c0 + 3] + ln1b[c0 + 3]);
        *(ushort4*)(x1 + (size_t)row * Cc + c0) = ov;
    } else {
        int i = (blk - NROW / 4) * 256 + threadIdx.x;
        if (i < na) { oa[i] = f2bf(a[i]); return; }
        i -= na;
        if (i < nb) { ob[i] = f2bf(b[i]); return; }
        i -= nb;
        if (i < nc) { oc[i] = f2bf(c[i]); return; }
        i -= nc;
        if (i < nd) { od[i] = f2bf(d[i]); }
    }
}

// ------- GEMM 128x128, triple-buffered counted-vmcnt pipeline (r15, frozen) -------
// EPI: 0 bias->bf16 | 2 bias+sigGELU->bf16 | 3 bias+res->fp32
template<int K, int EPI>
__global__ __launch_bounds__(256) void gemm128p(
        const u16* __restrict__ X, const u16* __restrict__ W,
        const float* __restrict__ bias,
        u16* __restrict__ outb, float* __restrict__ outf,
        const u16* __restrict__ res, int Nf, int nbn) {
    constexpr int NK = K / 32;
    __shared__ __align__(16) u16 smem[24576];
    u16* lA = smem;
    u16* lB = smem + 12288;
    const int nwg = gridDim.x;
    const int q8  = nwg >> 3;
    const int lid = (blockIdx.x & 7) * q8 + (blockIdx.x >> 3);
    const int bn  = (lid % nbn) * 128;
    const int bm  = (lid / nbn) * 128;
    const int tid = threadIdx.x, lane = tid & 63, wave = tid >> 6;
    const int wr = (wave >> 1) * 64, wc = (wave & 1) * 64;
    const int lr = lane & 15, lg = lane >> 4;

    const u16* xsrc[2]; const u16* wsrc[2]; int ldso[2];
    #pragma unroll
    for (int qq = 0; qq < 2; qq++) {
        const int cbase = wave * 128 + qq * 64;
        const int c   = cbase + lane;
        const int row = c >> 2, p = c & 3;
        const int gc  = p ^ ((row >> 1) & 3);
        xsrc[qq] = X + (size_t)(bm + row) * K + gc * 8;
        wsrc[qq] = W + (size_t)(bn + row) * K + gc * 8;
        ldso[qq] = cbase * 8;
    }
    auto stage = [&](int k0, int buf) {
        #pragma unroll
        for (int qq = 0; qq < 2; qq++) {
            gload16(xsrc[qq] + k0, lA + buf * 4096 + ldso[qq]);
            gload16(wsrc[qq] + k0, lB + buf * 4096 + ldso[qq]);
        }
    };

    stage(0, 0);
    stage(32, 1);

    const int rchunk = (lg ^ ((lr >> 1) & 3)) * 8;

    float4v acc[4][4] = {};
    #pragma unroll
    for (int k = 0; k < NK; ++k) {
        if (k + 1 < NK) asm volatile("s_waitcnt vmcnt(4)" ::: "memory");
        else            asm volatile("s_waitcnt vmcnt(0)" ::: "memory");
        __builtin_amdgcn_s_barrier();
        if (k + 2 < NK) stage((k + 2) * 32, (k + 2) % 3);
        const int cur = k % 3;
        short8v a[4], b[4];
        #pragma unroll
        for (int i = 0; i < 4; i++)
            a[i] = *(const short8v*)&lB[cur * 4096 + (wc + i * 16 + lr) * 32 + rchunk];
        #pragma unroll
        for (int j = 0; j < 4; j++)
            b[j] = *(const short8v*)&lA[cur * 4096 + (wr + j * 16 + lr) * 32 + rchunk];
        #pragma unroll
        for (int i = 0; i < 4; i++)
            #pragma unroll
            for (int j = 0; j < 4; j++)
                acc[i][j] = MFMA16(a[i], b[j], acc[i][j]);
    }

    if (EPI == 3) {
        #pragma unroll
        for (int i = 0; i < 4; i++) {
            const int n0 = bn + wc + i * 16 + lg * 4;
            const float4 bv = *(const float4*)&bias[n0];
            #pragma unroll
            for (int j = 0; j < 4; j++) {
                const int m = bm + wr + j * 16 + lr;
                const size_t o0 = (size_t)m * Nf + n0;
                ushort4 rv = *(const ushort4*)(res + o0);
                float4 o;
                o.x = acc[i][j][0] + bv.x + bf2f(rv.x);
                o.y = acc[i][j][1] + bv.y + bf2f(rv.y);
                o.z = acc[i][j][2] + bv.z + bf2f(rv.z);
                o.w = acc[i][j][3] + bv.w + bf2f(rv.w);
                *(float4*)(outf + o0) = o;
            }
        }
    } else {
        __syncthreads();
        u16* ot = smem;    // 128*136 = 17408 u16 <= 24576
        #pragma unroll
        for (int i = 0; i < 4; i++) {
            const int n0l = wc + i * 16 + lg * 4;
            const float4 bv = *(const float4*)&bias[bn + n0l];
            #pragma unroll
            for (int j = 0; j < 4; j++) {
                const int ml = wr + j * 16 + lr;
                float v0 = acc[i][j][0] + bv.x;
                float v1 = acc[i][j][1] + bv.y;
                float v2 = acc[i][j][2] + bv.z;
                float v3 = acc[i][j][3] + bv.w;
                if (EPI == 2) {
                    v0 = gelu_f(v0); v1 = gelu_f(v1); v2 = gelu_f(v2); v3 = gelu_f(v3);
                }
                ushort4 o;
                o.x = f2bf(v0); o.y = f2bf(v1); o.z = f2bf(v2); o.w = f2bf(v3);
                *(ushort4*)&ot[ml * 136 + n0l] = o;
            }
        }
        __syncthreads();
        #pragma unroll
        for (int i2 = 0; i2 < 8; i2++) {
            const int c   = i2 * 256 + tid;
            const int row = c >> 4, ch = c & 15;
            *(uint4*)(outb + (size_t)(bm + row) * Nf + bn + ch * 8) =
                *(const uint4*)&ot[row * 136 + ch * 8];
        }
    }
}

// ------- proj + residual + LN2 fused: x3 = LN(x1 + attb @ Wp^T + b) (r17) -------
__global__ __launch_bounds__(256) void proj_ln(
        const u16* __restrict__ X, const u16* __restrict__ W,
        const float* __restrict__ bias, const u16* __restrict__ res,
        const float* __restrict__ lnw, const float* __restrict__ lnb,
        u16* __restrict__ out) {
    constexpr int K = 256, NK = 8;
    __shared__ __align__(16) u16 smem[36864];
    u16* lA = smem;
    u16* lB = smem + 12288;
    const int nwg = gridDim.x;              // 512, %8==0
    const int q8  = nwg >> 3;
    const int lid = (blockIdx.x & 7) * q8 + (blockIdx.x >> 3);
    const int bm  = lid * 128;
    const int tid = threadIdx.x, lane = tid & 63, wave = tid >> 6;
    const int wr = (wave >> 1) * 64, wc = (wave & 1) * 128;
    const int lr = lane & 15, lg = lane >> 4;

    const u16* xsrc[2]; int ldsoA[2];
    #pragma unroll
    for (int qq = 0; qq < 2; qq++) {
        const int cbase = wave * 128 + qq * 64;
        const int c = cbase + lane;
        const int row = c >> 2, p = c & 3;
        const int gc = p ^ ((row >> 1) & 3);
        xsrc[qq] = X + (size_t)(bm + row) * K + gc * 8;
        ldsoA[qq] = cbase * 8;
    }
    const u16* wsrc[4]; int ldsoB[4];
    #pragma unroll
    for (int qq = 0; qq < 4; qq++) {
        const int cbase = wave * 256 + qq * 64;
        const int c = cbase + lane;
        const int row = c >> 2, p = c & 3;
        const int gc = p ^ ((row >> 1) & 3);
        wsrc[qq] = W + (size_t)row * K + gc * 8;
        ldsoB[qq] = cbase * 8;
    }
    auto stage = [&](int k0, int buf) {
        #pragma unroll
        for (int qq = 0; qq < 2; qq++)
            gload16(xsrc[qq] + k0, lA + buf * 4096 + ldsoA[qq]);
        #pragma unroll
        for (int qq = 0; qq < 4; qq++)
            gload16(wsrc[qq] + k0, lB + buf * 8192 + ldsoB[qq]);
    };
    stage(0, 0);
    stage(32, 1);

    const int rchunk = (lg ^ ((lr >> 1) & 3)) * 8;

    float4v acc[8][4] = {};
    #pragma unroll
    for (int k = 0; k < NK; ++k) {
        if (k + 1 < NK) asm volatile("s_waitcnt vmcnt(6)" ::: "memory");
        else            asm volatile("s_waitcnt vmcnt(0)" ::: "memory");
        __builtin_amdgcn_s_barrier();
        if (k + 2 < NK) stage((k + 2) * 32, (k + 2) % 3);
        const int cur = k % 3;
        short8v a[8], b[4];
        #pragma unroll
        for (int i = 0; i < 8; i++)
            a[i] = *(const short8v*)&lB[cur * 8192 + (wc + i * 16 + lr) * 32 + rchunk];
        #pragma unroll
        for (int j = 0; j < 4; j++)
            b[j] = *(const short8v*)&lA[cur * 4096 + (wr + j * 16 + lr) * 32 + rchunk];
        #pragma unroll
        for (int i = 0; i < 8; i++)
            #pragma unroll
            for (int j = 0; j < 4; j++)
                acc[i][j] = MFMA16(a[i], b[j], acc[i][j]);
    }

    #pragma unroll
    for (int i = 0; i < 8; i++) {
        const int n0 = wc + i * 16 + lg * 4;
        const float4 bv = *(const float4*)&bias[n0];
        #pragma unroll
        for (int j = 0; j < 4; j++) {
            const int m = bm + wr + j * 16 + lr;
            ushort4 rv = *(const ushort4*)(res + (size_t)m * 256 + n0);
            acc[i][j][0] += bv.x + bf2f(rv.x);
            acc[i][j][1] += bv.y + bf2f(rv.y);
            acc[i][j][2] += bv.z + bf2f(rv.z);
            acc[i][j][3] += bv.w + bf2f(rv.w);
        }
    }
    float ps[4], pq[4];
    #pragma unroll
    for (int j = 0; j < 4; j++) {
        float s = 0.f, q = 0.f;
        #pragma unroll
        for (int i = 0; i < 8; i++)
            #pragma unroll
            for (int r = 0; r < 4; r++) { float v = acc[i][j][r]; s += v; q += v * v; }
        s += __shfl_xor(s, 16); s += __shfl_xor(s, 32);
        q += __shfl_xor(q, 16); q += __shfl_xor(q, 32);
        ps[j] = s; pq[j] = q;
    }
    __syncthreads();
    float* pbuf = (float*)smem;
    const int half = wave & 1;
    #pragma unroll
    for (int j = 0; j < 4; j++) {
        const int rml = wr + j * 16 + lr;
        if (lg == 0) {
            pbuf[(rml * 2 + half) * 2 + 0] = ps[j];
            pbuf[(rml * 2 + half) * 2 + 1] = pq[j];
        }
    }
    __syncthreads();
    float mean_[4], rs_[4];
    #pragma unroll
    for (int j = 0; j < 4; j++) {
        const int rml = wr + j * 16 + lr;
        float s = pbuf[(rml * 2 + 0) * 2 + 0] + pbuf[(rml * 2 + 1) * 2 + 0];
        float q = pbuf[(rml * 2 + 0) * 2 + 1] + pbuf[(rml * 2 + 1) * 2 + 1];
        float mean = s * (1.f / 256.f);
        mean_[j] = mean;
        rs_[j] = rsqrtf(q * (1.f / 256.f) - mean * mean + 1e-5f);
    }
    __syncthreads();
    u16* ot = smem;             // 128*264 = 33792 u16 <= 36864
    #pragma unroll
    for (int i = 0; i < 8; i++) {
        const int n0 = wc + i * 16 + lg * 4;
        const float4 w4 = *(const float4*)&lnw[n0];
        const float4 b4 = *(const float4*)&lnb[n0];
        #pragma unroll
        for (int j = 0; j < 4; j++) {
            const int rml = wr + j * 16 + lr;
            ushort4 o;
            o.x = f2bf((acc[i][j][0] - mean_[j]) * rs_[j] * w4.x + b4.x);
            o.y = f2bf((acc[i][j][1] - mean_[j]) * rs_[j] * w4.y + b4.y);
            o.z = f2bf((acc[i][j][2] - mean_[j]) * rs_[j] * w4.z + b4.z);
            o.w = f2bf((acc[i][j][3] - mean_[j]) * rs_[j] * w4.w + b4.w);
            *(ushort4*)&ot[rml * 264 + n0] = o;
        }
    }
    __syncthreads();
    #pragma unroll
    for (int i2 = 0; i2 < 16; i2++) {
        const int c = i2 * 256 + tid;
        const int row = c >> 5, ch = c & 31;
        *(uint4*)(out + (size_t)(bm + row) * 256 + ch * 8) =
            *(const uint4*)&ot[row * 264 + ch * 8];
    }
}

// ---- MFMA attention, head-split: one block per (b,a,h), 4 waves (r16) ----
__global__ __launch_bounds__(256) void attn_mfma_h(
        const u16* __restrict__ qkv, const unsigned char* __restrict__ mask,
        u16* __restrict__ out) {
    __shared__ u16 sk[128][32];
    __shared__ u16 svt[32][136];
    __shared__ u16 sp[4][32][136];
    __shared__ unsigned char smask[128];
    const int blk = blockIdx.x;
    const int h   = blk & (Hc - 1);
    const int ba  = blk >> 3;
    const size_t rowbase = (size_t)ba * Tc;
    const int tid  = threadIdx.x;
    const int lane = tid & 63;
    const int wave = tid >> 6;
    const int wq0  = wave * 32;
    const int lrow = lane & 15, lg = lane >> 4;
    if (tid < 128) smask[tid] = mask[rowbase + tid];

    const float scale  = 0.17677669529663687f;
    const float inv128 = 1.0f / 128.0f;
    const float4v zero4 = {0.f, 0.f, 0.f, 0.f};

    {
        const int r = tid >> 1, half = tid & 1;
        const u16* gbase = qkv + (rowbase + r) * 768 + h * 32 + half * 16;
        uint4 k0 = *(const uint4*)(gbase + 256);
        uint4 k1 = *(const uint4*)(gbase + 256 + 8);
        *(uint4*)&sk[r][half * 16]     = k0;
        *(uint4*)&sk[r][half * 16 + 8] = k1;
        uint4 v0 = *(const uint4*)(gbase + 512);
        uint4 v1 = *(const uint4*)(gbase + 512 + 8);
        u16 vt[16];
        *(uint4*)&vt[0] = v0; *(uint4*)&vt[8] = v1;
        #pragma unroll
        for (int e = 0; e < 16; e++) svt[half * 16 + e][r] = vt[e];
    }
    __syncthreads();

    short8v a0, a1;
    {
        const u16* qp0 = qkv + (rowbase + wq0 + lrow) * 768 + h * 32 + lg * 8;
        const u16* qp1 = qp0 + 16 * 768;
        a0 = *(const short8v*)qp0;
        a1 = *(const short8v*)qp1;
    }
    float4v s_acc[2][8];
    #pragma unroll
    for (int j = 0; j < 8; j++) {
        short8v bj = *(const short8v*)&sk[j * 16 + lrow][lg * 8];
        s_acc[0][j] = MFMA16(a0, bj, zero4);
        s_acc[1][j] = MFMA16(a1, bj, zero4);
    }

    #pragma unroll
    for (int i = 0; i < 2; i++) {
        #pragma unroll
        for (int r = 0; r < 4; r++) {
            float m = s_acc[i][0][r];
            #pragma unroll
            for (int j = 1; j < 8; j++) m = fmaxf(m, s_acc[i][j][r]);
            #pragma unroll
            for (int off = 1; off < 16; off <<= 1) m = fmaxf(m, __shfl_xor(m, off));
            float sum = 0.f;
            #pragma unroll
            for (int j = 0; j < 8; j++) {
                float e = __expf((s_acc[i][j][r] - m) * scale);
                sum += e;
                s_acc[i][j][r] = e;
            }
            #pragma unroll
            for (int off = 1; off < 16; off <<= 1) sum += __shfl_xor(sum, off);
            const int qloc = i * 16 + lg * 4 + r;
            const bool mk = smask[wq0 + qloc] != 0;
            const float invs = 1.f / sum;
            #pragma unroll
            for (int j = 0; j < 8; j++) {
                float pv = mk ? inv128 : s_acc[i][j][r] * invs;
                sp[wave][qloc][j * 16 + lrow] = f2bf(pv);
            }
        }
    }

    float4v o_acc[2][2] = {};
    #pragma unroll
    for (int t = 0; t < 4; t++) {
        short8v pa0 = *(const short8v*)&sp[wave][lrow][t * 32 + lg * 8];
        short8v pa1 = *(const short8v*)&sp[wave][16 + lrow][t * 32 + lg * 8];
        short8v vb0 = *(const short8v*)&svt[lrow][t * 32 + lg * 8];
        short8v vb1 = *(const short8v*)&svt[16 + lrow][t * 32 + lg * 8];
        o_acc[0][0] = MFMA16(pa0, vb0, o_acc[0][0]);
        o_acc[0][1] = MFMA16(pa0, vb1, o_acc[0][1]);
        o_acc[1][0] = MFMA16(pa1, vb0, o_acc[1][0]);
        o_acc[1][1] = MFMA16(pa1, vb1, o_acc[1][1]);
    }

    #pragma unroll
    for (int i = 0; i < 2; i++)
        #pragma unroll
        for (int n = 0; n < 2; n++)
            #pragma unroll
            for (int r = 0; r < 4; r++) {
                size_t row = rowbase + wq0 + i * 16 + lg * 4 + r;
                int col = h * 32 + n * 16 + lrow;
                out[row * 256 + col] = f2bf(o_acc[i][n][r]);
            }
}

extern "C" void kernel_launch(void* const* d_in, const int* in_sizes, int n_in,
                              void* d_out, int out_size, void* d_ws, size_t ws_size,
                              hipStream_t stream) {
    const float* x      = (const float*)d_in[0];
    const unsigned char* mask = (const unsigned char*)d_in[1];
    const float* ln1_w  = (const float*)d_in[2];
    const float* ln1_b  = (const float*)d_in[3];
    const float* qkv_w  = (const float*)d_in[4];
    const float* qkv_b  = (const float*)d_in[5];
    const float* proj_w = (const float*)d_in[6];
    const float* proj_b = (const float*)d_in[7];
    const float* ln2_w  = (const float*)d_in[8];
    const float* ln2_b  = (const float*)d_in[9];
    const float* fc1_w  = (const float*)d_in[10];
    const float* fc1_b  = (const float*)d_in[11];
    const float* fc2_w  = (const float*)d_in[12];
    const float* fc2_b  = (const float*)d_in[13];
    float* out = (float*)d_out;

    char* ws = (char*)d_ws;
    size_t off = 0;
    auto alloc = [&](size_t elems) -> u16* {
        u16* p = (u16*)(ws + off);
        off += ((elems * 2 + 255) / 256) * 256;
        return p;
    };
    u16* wqb  = alloc(768 * 256);
    u16* wpb  = alloc(256 * 256);
    u16* w1b  = alloc(1024 * 256);
    u16* w2b  = alloc(256 * 1024);
    u16* x1b  = alloc((size_t)NROW * Cc);
    u16* qkvb = alloc((size_t)NROW * 3 * Cc);
    u16* attb = alloc((size_t)NROW * Cc);
    u16* x3b  = alloc((size_t)NROW * Cc);
    u16* hb   = qkvb;   // fc1 output reuses qkv(3NC)+attn(NC) region = 4NC

    // prep: LN1 (16384 blocks) + weight casts (3072 blocks), one launch
    prep_kernel<<<NROW / 4 + 3072, 256, 0, stream>>>(
        x, ln1_w, ln1_b, x1b,
        qkv_w, 196608, proj_w, 65536, fc1_w, 262144, fc2_w, 262144,
        wqb, wpb, w1b, w2b);
    // qkv: M=65536, N=768 -> 512*6 blocks
    gemm128p<256, 0><<<512 * 6, 256, 0, stream>>>(
        x1b, wqb, qkv_b, qkvb, nullptr, nullptr, 768, 6);
    attn_mfma_h<<<Bc * Ac * Hc, 256, 0, stream>>>(qkvb, mask, attb);
    // proj + residual(x1) + LN2 fused -> x3
    proj_ln<<<512, 256, 0, stream>>>(
        attb, wpb, proj_b, x1b, ln2_w, ln2_b, x3b);
    // fc1 + GELU: N=1024 -> 512*8 blocks
    gemm128p<256, 2><<<512 * 8, 256, 0, stream>>>(
        x3b, w1b, fc1_b, hb, nullptr, nullptr, 1024, 8);
    // fc2 + residual(x3) -> fp32 out: K=1024 (32 iters), N=256 -> 512*2 blocks
    gemm128p<1024, 3><<<512 * 2, 256, 0, stream>>>(
        hb, w2b, fc2_b, nullptr, out, x3b, 256, 2);
}

// Round 19
// 272.573 us; speedup vs baseline: 1.0097x; 1.0097x over previous
//
#include <hip/hip_runtime.h>
#include <hip/hip_bf16.h>

typedef unsigned short u16;
typedef unsigned int   u32;

static constexpr int Bc = 8, Ac = 64, Tc = 128, Cc = 256, Hc = 8;
static constexpr int NROW = Bc * Ac * Tc;   // 65536 tokens
static constexpr int DH = Cc / Hc;          // 32

__device__ __forceinline__ float bf2f(u16 h) {
    u32 u = ((u32)h) << 16; float f; __builtin_memcpy(&f, &u, 4); return f;
}
__device__ __forceinline__ u16 f2bf(float f) {
    u32 u; __builtin_memcpy(&u, &f, 4);
    u += 0x7fffu + ((u >> 16) & 1u);   // RNE
    return (u16)(u >> 16);
}

// sigmoid-GELU: x*sigmoid(1.702x); error budget verified r15-r17 (absmax 0.052)
__device__ __forceinline__ float gelu_f(float x) {
    return x / (1.0f + __expf(-1.702f * x));
}

typedef __attribute__((ext_vector_type(8))) short  short8v;
typedef __attribute__((ext_vector_type(4))) float  float4v;

__device__ __forceinline__ void gload16(const void* g, const void* lds) {
    __builtin_amdgcn_global_load_lds(
        (const __attribute__((address_space(1))) void*)g,
        (__attribute__((address_space(3))) void*)lds, 16, 0, 0);
}

#define MFMA16(a, b, c) __builtin_amdgcn_mfma_f32_16x16x32_bf16((a), (b), (c), 0, 0, 0)

// ---------------- cast all weights fp32 -> bf16, one launch ----------------
__global__ void cast4_kernel(const float* __restrict__ a, int na,
                             const float* __restrict__ b, int nb,
                             const float* __restrict__ c, int nc,
                             const float* __restrict__ d, int nd,
                             u16* oa, u16* ob, u16* oc, u16* od) {
    int i = blockIdx.x * 256 + threadIdx.x;
    if (i < na) { oa[i] = f2bf(a[i]); return; }
    i -= na;
    if (i < nb) { ob[i] = f2bf(b[i]); return; }
    i -= nb;
    if (i < nc) { oc[i] = f2bf(c[i]); return; }
    i -= nc;
    if (i < nd) { od[i] = f2bf(d[i]); }
}

// ---------------- LayerNorm, fp32 input -> bf16 out ----------------
__global__ __launch_bounds__(256) void ln_f32(const float* __restrict__ in,
        const float* __restrict__ w, const float* __restrict__ b,
        u16* __restrict__ out) {
    int row  = blockIdx.x * 4 + (threadIdx.x >> 6);
    int lane = threadIdx.x & 63;
    const float* rp = in + (size_t)row * Cc + lane * 4;
    float4 v = *(const float4*)rp;
    float s  = v.x + v.y + v.z + v.w;
    float sq = v.x * v.x + v.y * v.y + v.z * v.z + v.w * v.w;
    for (int off = 32; off; off >>= 1) { s += __shfl_xor(s, off); sq += __shfl_xor(sq, off); }
    float mean = s * (1.f / Cc);
    float rs = rsqrtf(sq * (1.f / Cc) - mean * mean + 1e-5f);
    int c0 = lane * 4;
    ushort4 ov;
    ov.x = f2bf((v.x - mean) * rs * w[c0 + 0] + b[c0 + 0]);
    ov.y = f2bf((v.y - mean) * rs * w[c0 + 1] + b[c0 + 1]);
    ov.z = f2bf((v.z - mean) * rs * w[c0 + 2] + b[c0 + 2]);
    ov.w = f2bf((v.w - mean) * rs * w[c0 + 3] + b[c0 + 3]);
    *(ushort4*)(out + (size_t)row * Cc + c0) = ov;
}

// ------- GEMM 128x128, triple-buffered counted-vmcnt pipeline (r15, frozen) -------
// EPI: 0 bias->bf16 | 2 bias+sigGELU->bf16 | 3 bias+res->fp32
template<int K, int EPI>
__global__ __launch_bounds__(256) void gemm128p(
        const u16* __restrict__ X, const u16* __restrict__ W,
        const float* __restrict__ bias,
        u16* __restrict__ outb, float* __restrict__ outf,
        const u16* __restrict__ res, int Nf, int nbn) {
    constexpr int NK = K / 32;
    __shared__ __align__(16) u16 smem[24576];
    u16* lA = smem;
    u16* lB = smem + 12288;
    const int nwg = gridDim.x;
    const int q8  = nwg >> 3;
    const int lid = (blockIdx.x & 7) * q8 + (blockIdx.x >> 3);
    const int bn  = (lid % nbn) * 128;
    const int bm  = (lid / nbn) * 128;
    const int tid = threadIdx.x, lane = tid & 63, wave = tid >> 6;
    const int wr = (wave >> 1) * 64, wc = (wave & 1) * 64;
    const int lr = lane & 15, lg = lane >> 4;

    const u16* xsrc[2]; const u16* wsrc[2]; int ldso[2];
    #pragma unroll
    for (int qq = 0; qq < 2; qq++) {
        const int cbase = wave * 128 + qq * 64;
        const int c   = cbase + lane;
        const int row = c >> 2, p = c & 3;
        const int gc  = p ^ ((row >> 1) & 3);
        xsrc[qq] = X + (size_t)(bm + row) * K + gc * 8;
        wsrc[qq] = W + (size_t)(bn + row) * K + gc * 8;
        ldso[qq] = cbase * 8;
    }
    auto stage = [&](int k0, int buf) {
        #pragma unroll
        for (int qq = 0; qq < 2; qq++) {
            gload16(xsrc[qq] + k0, lA + buf * 4096 + ldso[qq]);
            gload16(wsrc[qq] + k0, lB + buf * 4096 + ldso[qq]);
        }
    };

    stage(0, 0);
    stage(32, 1);

    const int rchunk = (lg ^ ((lr >> 1) & 3)) * 8;

    float4v acc[4][4] = {};
    #pragma unroll
    for (int k = 0; k < NK; ++k) {
        if (k + 1 < NK) asm volatile("s_waitcnt vmcnt(4)" ::: "memory");
        else            asm volatile("s_waitcnt vmcnt(0)" ::: "memory");
        __builtin_amdgcn_s_barrier();
        if (k + 2 < NK) stage((k + 2) * 32, (k + 2) % 3);
        const int cur = k % 3;
        short8v a[4], b[4];
        #pragma unroll
        for (int i = 0; i < 4; i++)
            a[i] = *(const short8v*)&lB[cur * 4096 + (wc + i * 16 + lr) * 32 + rchunk];
        #pragma unroll
        for (int j = 0; j < 4; j++)
            b[j] = *(const short8v*)&lA[cur * 4096 + (wr + j * 16 + lr) * 32 + rchunk];
        #pragma unroll
        for (int i = 0; i < 4; i++)
            #pragma unroll
            for (int j = 0; j < 4; j++)
                acc[i][j] = MFMA16(a[i], b[j], acc[i][j]);
    }

    if (EPI == 3) {
        #pragma unroll
        for (int i = 0; i < 4; i++) {
            const int n0 = bn + wc + i * 16 + lg * 4;
            const float4 bv = *(const float4*)&bias[n0];
            #pragma unroll
            for (int j = 0; j < 4; j++) {
                const int m = bm + wr + j * 16 + lr;
                const size_t o0 = (size_t)m * Nf + n0;
                ushort4 rv = *(const ushort4*)(res + o0);
                float4 o;
                o.x = acc[i][j][0] + bv.x + bf2f(rv.x);
                o.y = acc[i][j][1] + bv.y + bf2f(rv.y);
                o.z = acc[i][j][2] + bv.z + bf2f(rv.z);
                o.w = acc[i][j][3] + bv.w + bf2f(rv.w);
                *(float4*)(outf + o0) = o;
            }
        }
    } else {
        __syncthreads();
        u16* ot = smem;    // 128*136 = 17408 u16 <= 24576
        #pragma unroll
        for (int i = 0; i < 4; i++) {
            const int n0l = wc + i * 16 + lg * 4;
            const float4 bv = *(const float4*)&bias[bn + n0l];
            #pragma unroll
            for (int j = 0; j < 4; j++) {
                const int ml = wr + j * 16 + lr;
                float v0 = acc[i][j][0] + bv.x;
                float v1 = acc[i][j][1] + bv.y;
                float v2 = acc[i][j][2] + bv.z;
                float v3 = acc[i][j][3] + bv.w;
                if (EPI == 2) {
                    v0 = gelu_f(v0); v1 = gelu_f(v1); v2 = gelu_f(v2); v3 = gelu_f(v3);
                }
                ushort4 o;
                o.x = f2bf(v0); o.y = f2bf(v1); o.z = f2bf(v2); o.w = f2bf(v3);
                *(ushort4*)&ot[ml * 136 + n0l] = o;
            }
        }
        __syncthreads();
        #pragma unroll
        for (int i2 = 0; i2 < 8; i2++) {
            const int c   = i2 * 256 + tid;
            const int row = c >> 4, ch = c & 15;
            *(uint4*)(outb + (size_t)(bm + row) * Nf + bn + ch * 8) =
                *(const uint4*)&ot[row * 136 + ch * 8];
        }
    }
}

// ------- proj + residual + LN2 fused: x3 = LN(x1 + attb @ Wp^T + b) (r17) -------
__global__ __launch_bounds__(256) void proj_ln(
        const u16* __restrict__ X, const u16* __restrict__ W,
        const float* __restrict__ bias, const u16* __restrict__ res,
        const float* __restrict__ lnw, const float* __restrict__ lnb,
        u16* __restrict__ out) {
    constexpr int K = 256, NK = 8;
    __shared__ __align__(16) u16 smem[36864];
    u16* lA = smem;
    u16* lB = smem + 12288;
    const int nwg = gridDim.x;              // 512, %8==0
    const int q8  = nwg >> 3;
    const int lid = (blockIdx.x & 7) * q8 + (blockIdx.x >> 3);
    const int bm  = lid * 128;
    const int tid = threadIdx.x, lane = tid & 63, wave = tid >> 6;
    const int wr = (wave >> 1) * 64, wc = (wave & 1) * 128;
    const int lr = lane & 15, lg = lane >> 4;

    const u16* xsrc[2]; int ldsoA[2];
    #pragma unroll
    for (int qq = 0; qq < 2; qq++) {
        const int cbase = wave * 128 + qq * 64;
        const int c = cbase + lane;
        const int row = c >> 2, p = c & 3;
        const int gc = p ^ ((row >> 1) & 3);
        xsrc[qq] = X + (size_t)(bm + row) * K + gc * 8;
        ldsoA[qq] = cbase * 8;
    }
    const u16* wsrc[4]; int ldsoB[4];
    #pragma unroll
    for (int qq = 0; qq < 4; qq++) {
        const int cbase = wave * 256 + qq * 64;
        const int c = cbase + lane;
        const int row = c >> 2, p = c & 3;
        const int gc = p ^ ((row >> 1) & 3);
        wsrc[qq] = W + (size_t)row * K + gc * 8;
        ldsoB[qq] = cbase * 8;
    }
    auto stage = [&](int k0, int buf) {
        #pragma unroll
        for (int qq = 0; qq < 2; qq++)
            gload16(xsrc[qq] + k0, lA + buf * 4096 + ldsoA[qq]);
        #pragma unroll
        for (int qq = 0; qq < 4; qq++)
            gload16(wsrc[qq] + k0, lB + buf * 8192 + ldsoB[qq]);
    };
    stage(0, 0);
    stage(32, 1);

    const int rchunk = (lg ^ ((lr >> 1) & 3)) * 8;

    float4v acc[8][4] = {};
    #pragma unroll
    for (int k = 0; k < NK; ++k) {
        if (k + 1 < NK) asm volatile("s_waitcnt vmcnt(6)" ::: "memory");
        else            asm volatile("s_waitcnt vmcnt(0)" ::: "memory");
        __builtin_amdgcn_s_barrier();
        if (k + 2 < NK) stage((k + 2) * 32, (k + 2) % 3);
        const int cur = k % 3;
        short8v a[8], b[4];
        #pragma unroll
        for (int i = 0; i < 8; i++)
            a[i] = *(const short8v*)&lB[cur * 8192 + (wc + i * 16 + lr) * 32 + rchunk];
        #pragma unroll
        for (int j = 0; j < 4; j++)
            b[j] = *(const short8v*)&lA[cur * 4096 + (wr + j * 16 + lr) * 32 + rchunk];
        #pragma unroll
        for (int i = 0; i < 8; i++)
            #pragma unroll
            for (int j = 0; j < 4; j++)
                acc[i][j] = MFMA16(a[i], b[j], acc[i][j]);
    }

    #pragma unroll
    for (int i = 0; i < 8; i++) {
        const int n0 = wc + i * 16 + lg * 4;
        const float4 bv = *(const float4*)&bias[n0];
        #pragma unroll
        for (int j = 0; j < 4; j++) {
            const int m = bm + wr + j * 16 + lr;
            ushort4 rv = *(const ushort4*)(res + (size_t)m * 256 + n0);
            acc[i][j][0] += bv.x + bf2f(rv.x);
            acc[i][j][1] += bv.y + bf2f(rv.y);
            acc[i][j][2] += bv.z + bf2f(rv.z);
            acc[i][j][3] += bv.w + bf2f(rv.w);
        }
    }
    float ps[4], pq[4];
    #pragma unroll
    for (int j = 0; j < 4; j++) {
        float s = 0.f, q = 0.f;
        #pragma unroll
        for (int i = 0; i < 8; i++)
            #pragma unroll
            for (int r = 0; r < 4; r++) { float v = acc[i][j][r]; s += v; q += v * v; }
        s += __shfl_xor(s, 16); s += __shfl_xor(s, 32);
        q += __shfl_xor(q, 16); q += __shfl_xor(q, 32);
        ps[j] = s; pq[j] = q;
    }
    __syncthreads();
    float* pbuf = (float*)smem;
    const int half = wave & 1;
    #pragma unroll
    for (int j = 0; j < 4; j++) {
        const int rml = wr + j * 16 + lr;
        if (lg == 0) {
            pbuf[(rml * 2 + half) * 2 + 0] = ps[j];
            pbuf[(rml * 2 + half) * 2 + 1] = pq[j];
        }
    }
    __syncthreads();
    float mean_[4], rs_[4];
    #pragma unroll
    for (int j = 0; j < 4; j++) {
        const int rml = wr + j * 16 + lr;
        float s = pbuf[(rml * 2 + 0) * 2 + 0] + pbuf[(rml * 2 + 1) * 2 + 0];
        float q = pbuf[(rml * 2 + 0) * 2 + 1] + pbuf[(rml * 2 + 1) * 2 + 1];
        float mean = s * (1.f / 256.f);
        mean_[j] = mean;
        rs_[j] = rsqrtf(q * (1.f / 256.f) - mean * mean + 1e-5f);
    }
    __syncthreads();
    u16* ot = smem;             // 128*264 = 33792 u16 <= 36864
    #pragma unroll
    for (int i = 0; i < 8; i++) {
        const int n0 = wc + i * 16 + lg * 4;
        const float4 w4 = *(const float4*)&lnw[n0];
        const float4 b4 = *(const float4*)&lnb[n0];
        #pragma unroll
        for (int j = 0; j < 4; j++) {
            const int rml = wr + j * 16 + lr;
            ushort4 o;
            o.x = f2bf((acc[i][j][0] - mean_[j]) * rs_[j] * w4.x + b4.x);
            o.y = f2bf((acc[i][j][1] - mean_[j]) * rs_[j] * w4.y + b4.y);
            o.z = f2bf((acc[i][j][2] - mean_[j]) * rs_[j] * w4.z + b4.z);
            o.w = f2bf((acc[i][j][3] - mean_[j]) * rs_[j] * w4.w + b4.w);
            *(ushort4*)&ot[rml * 264 + n0] = o;
        }
    }
    __syncthreads();
    #pragma unroll
    for (int i2 = 0; i2 < 16; i2++) {
        const int c = i2 * 256 + tid;
        const int row = c >> 5, ch = c & 31;
        *(uint4*)(out + (size_t)(bm + row) * 256 + ch * 8) =
            *(const uint4*)&ot[row * 264 + ch * 8];
    }
}

// ---- MFMA attention, head-split (r16) + swapped-PV vector store (r19) ----
__global__ __launch_bounds__(256) void attn_mfma_h(
        const u16* __restrict__ qkv, const unsigned char* __restrict__ mask,
        u16* __restrict__ out) {
    __shared__ u16 sk[128][32];
    __shared__ u16 svt[32][136];
    __shared__ u16 sp[4][32][136];
    __shared__ unsigned char smask[128];
    const int blk = blockIdx.x;
    const int h   = blk & (Hc - 1);
    const int ba  = blk >> 3;
    const size_t rowbase = (size_t)ba * Tc;
    const int tid  = threadIdx.x;
    const int lane = tid & 63;
    const int wave = tid >> 6;
    const int wq0  = wave * 32;
    const int lrow = lane & 15, lg = lane >> 4;
    if (tid < 128) smask[tid] = mask[rowbase + tid];

    const float scale  = 0.17677669529663687f;
    const float inv128 = 1.0f / 128.0f;
    const float4v zero4 = {0.f, 0.f, 0.f, 0.f};

    {
        const int r = tid >> 1, half = tid & 1;
        const u16* gbase = qkv + (rowbase + r) * 768 + h * 32 + half * 16;
        uint4 k0 = *(const uint4*)(gbase + 256);
        uint4 k1 = *(const uint4*)(gbase + 256 + 8);
        *(uint4*)&sk[r][half * 16]     = k0;
        *(uint4*)&sk[r][half * 16 + 8] = k1;
        uint4 v0 = *(const uint4*)(gbase + 512);
        uint4 v1 = *(const uint4*)(gbase + 512 + 8);
        u16 vt[16];
        *(uint4*)&vt[0] = v0; *(uint4*)&vt[8] = v1;
        #pragma unroll
        for (int e = 0; e < 16; e++) svt[half * 16 + e][r] = vt[e];
    }
    __syncthreads();

    short8v a0, a1;
    {
        const u16* qp0 = qkv + (rowbase + wq0 + lrow) * 768 + h * 32 + lg * 8;
        const u16* qp1 = qp0 + 16 * 768;
        a0 = *(const short8v*)qp0;
        a1 = *(const short8v*)qp1;
    }
    float4v s_acc[2][8];
    #pragma unroll
    for (int j = 0; j < 8; j++) {
        short8v bj = *(const short8v*)&sk[j * 16 + lrow][lg * 8];
        s_acc[0][j] = MFMA16(a0, bj, zero4);
        s_acc[1][j] = MFMA16(a1, bj, zero4);
    }

    #pragma unroll
    for (int i = 0; i < 2; i++) {
        #pragma unroll
        for (int r = 0; r < 4; r++) {
            float m = s_acc[i][0][r];
            #pragma unroll
            for (int j = 1; j < 8; j++) m = fmaxf(m, s_acc[i][j][r]);
            #pragma unroll
            for (int off = 1; off < 16; off <<= 1) m = fmaxf(m, __shfl_xor(m, off));
            float sum = 0.f;
            #pragma unroll
            for (int j = 0; j < 8; j++) {
                float e = __expf((s_acc[i][j][r] - m) * scale);
                sum += e;
                s_acc[i][j][r] = e;
            }
            #pragma unroll
            for (int off = 1; off < 16; off <<= 1) sum += __shfl_xor(sum, off);
            const int qloc = i * 16 + lg * 4 + r;
            const bool mk = smask[wq0 + qloc] != 0;
            const float invs = 1.f / sum;
            #pragma unroll
            for (int j = 0; j < 8; j++) {
                float pv = mk ? inv128 : s_acc[i][j][r] * invs;
                sp[wave][qloc][j * 16 + lrow] = f2bf(pv);
            }
        }
    }

    // O = P V, SWAPPED operands: D rows = d (V frag), cols = q (P frag) ->
    // each fragment's 4 values = 4 consecutive d at fixed q -> ushort4 store.
    float4v o_acc[2][2] = {};   // [i = q-block][n = d-block]
    #pragma unroll
    for (int t = 0; t < 4; t++) {
        short8v pa0 = *(const short8v*)&sp[wave][lrow][t * 32 + lg * 8];
        short8v pa1 = *(const short8v*)&sp[wave][16 + lrow][t * 32 + lg * 8];
        short8v vb0 = *(const short8v*)&svt[lrow][t * 32 + lg * 8];
        short8v vb1 = *(const short8v*)&svt[16 + lrow][t * 32 + lg * 8];
        o_acc[0][0] = MFMA16(vb0, pa0, o_acc[0][0]);
        o_acc[0][1] = MFMA16(vb1, pa0, o_acc[0][1]);
        o_acc[1][0] = MFMA16(vb0, pa1, o_acc[1][0]);
        o_acc[1][1] = MFMA16(vb1, pa1, o_acc[1][1]);
    }

    #pragma unroll
    for (int i = 0; i < 2; i++)
        #pragma unroll
        for (int n = 0; n < 2; n++) {
            const size_t row = rowbase + wq0 + i * 16 + lrow;   // q
            const int col = h * 32 + n * 16 + lg * 4;            // d0
            ushort4 o;
            o.x = f2bf(o_acc[i][n][0]);
            o.y = f2bf(o_acc[i][n][1]);
            o.z = f2bf(o_acc[i][n][2]);
            o.w = f2bf(o_acc[i][n][3]);
            *(ushort4*)(out + row * 256 + col) = o;
        }
}

extern "C" void kernel_launch(void* const* d_in, const int* in_sizes, int n_in,
                              void* d_out, int out_size, void* d_ws, size_t ws_size,
                              hipStream_t stream) {
    const float* x      = (const float*)d_in[0];
    const unsigned char* mask = (const unsigned char*)d_in[1];
    const float* ln1_w  = (const float*)d_in[2];
    const float* ln1_b  = (const float*)d_in[3];
    const float* qkv_w  = (const float*)d_in[4];
    const float* qkv_b  = (const float*)d_in[5];
    const float* proj_w = (const float*)d_in[6];
    const float* proj_b = (const float*)d_in[7];
    const float* ln2_w  = (const float*)d_in[8];
    const float* ln2_b  = (const float*)d_in[9];
    const float* fc1_w  = (const float*)d_in[10];
    const float* fc1_b  = (const float*)d_in[11];
    const float* fc2_w  = (const float*)d_in[12];
    const float* fc2_b  = (const float*)d_in[13];
    float* out = (float*)d_out;

    char* ws = (char*)d_ws;
    size_t off = 0;
    auto alloc = [&](size_t elems) -> u16* {
        u16* p = (u16*)(ws + off);
        off += ((elems * 2 + 255) / 256) * 256;
        return p;
    };
    u16* wqb  = alloc(768 * 256);
    u16* wpb  = alloc(256 * 256);
    u16* w1b  = alloc(1024 * 256);
    u16* w2b  = alloc(256 * 1024);
    u16* x1b  = alloc((size_t)NROW * Cc);
    u16* qkvb = alloc((size_t)NROW * 3 * Cc);
    u16* attb = alloc((size_t)NROW * Cc);
    u16* x3b  = alloc((size_t)NROW * Cc);
    u16* hb   = qkvb;   // fc1 output reuses qkv(3NC)+attn(NC) region = 4NC

    cast4_kernel<<<(786432 + 255) / 256, 256, 0, stream>>>(
        qkv_w, 196608, proj_w, 65536, fc1_w, 262144, fc2_w, 262144,
        wqb, wpb, w1b, w2b);
    ln_f32<<<NROW / 4, 256, 0, stream>>>(x, ln1_w, ln1_b, x1b);
    // qkv: M=65536, N=768 -> 512*6 blocks
    gemm128p<256, 0><<<512 * 6, 256, 0, stream>>>(
        x1b, wqb, qkv_b, qkvb, nullptr, nullptr, 768, 6);
    attn_mfma_h<<<Bc * Ac * Hc, 256, 0, stream>>>(qkvb, mask, attb);
    // proj + residual(x1) + LN2 fused -> x3
    proj_ln<<<512, 256, 0, stream>>>(
        attb, wpb, proj_b, x1b, ln2_w, ln2_b, x3b);
    // fc1 + GELU: N=1024 -> 512*8 blocks
    gemm128p<256, 2><<<512 * 8, 256, 0, stream>>>(
        x3b, w1b, fc1_b, hb, nullptr, nullptr, 1024, 8);
    // fc2 + residual(x3) -> fp32 out: K=1024 (32 iters), N=256 -> 512*2 blocks
    gemm128p<1024, 3><<<512 * 2, 256, 0, stream>>>(
        hb, w2b, fc2_b, nullptr, out, x3b, 256, 2);
}